// Round 5
// baseline (110.236 us; speedup 1.0000x reference)
//
#include <hip/hip_runtime.h>

// 3-level separable 2D DWT, bior3.5, mode='periodization'.
// out[i] = sum_j f[j] * x[(2i+1-j) mod N] along each axis.
// v5: v4 prefetch pipeline + role-split waves (threads 128..255 stage, 0..127
//     column-pass with 4 rows/thread), TRS=43 (odd pitch -> bank-uniform
//     transposed reads AND 2-way-free writes). 2 barriers/step; the next
//     step's ds_writes overlap the current step's column pass + stores.

#define OW 32                  // output cols per block
#define OHS 16                 // output rows per step
#define NSTEP 4                // steps per block -> 64 output rows per block
#define ROWS_PB (OHS * NSTEP)
#define IN_ROWS 42             // 2*OHS + 10 staged input rows per step
#define QPR 20                 // float4 quads per staged row (80 cols)
#define NQ (IN_ROWS * QPR)     // 840 staged quads per step
#define SPITCH 84              // s_in dword pitch (b128 reads land 8 touches/bank = min)
#define TRS 43                 // transposed pitch, odd -> all-32-bank coverage

template <int N>
__global__ __launch_bounds__(256, 6) void dwt2_level(
    const float* __restrict__ src,
    float* __restrict__ aa, float* __restrict__ da,
    float* __restrict__ ad, float* __restrict__ dd)
{
    constexpr float SQ2 = 1.41421356237309504880f;
    constexpr float c_lo[12] = {
        -20.f * SQ2 / 2048.f,  60.f * SQ2 / 2048.f,   76.f * SQ2 / 2048.f,
        -388.f * SQ2 / 2048.f, -104.f * SQ2 / 2048.f, 1400.f * SQ2 / 2048.f,
        1400.f * SQ2 / 2048.f, -104.f * SQ2 / 2048.f, -388.f * SQ2 / 2048.f,
        76.f * SQ2 / 2048.f,   60.f * SQ2 / 2048.f,   -20.f * SQ2 / 2048.f };
    constexpr float c_hi4[4] = { -SQ2 / 8.f, 3.f * SQ2 / 8.f, -3.f * SQ2 / 8.f, SQ2 / 8.f };

    constexpr int h    = N >> 1;
    constexpr int mask = N - 1;

    const int bc  = blockIdx.z;
    const int j0  = blockIdx.x * OW;
    const int i0  = blockIdx.y * ROWS_PB;
    const int tid = threadIdx.x;

    __shared__ float s_in[IN_ROWS * SPITCH];   // 14.1 KB
    __shared__ float s_loT[OW * TRS];          // 5.4 KB
    __shared__ float s_hiT[OW * TRS];          // 5.4 KB  (24.6 KB -> 6 blocks/CU)

    const float* img = src + (unsigned)bc * (unsigned)(N * N);
    const int c0 = 2 * j0 - 12;   // quad-aligned col base (multiple of 4)

    // Staged quad q: contiguous, 16B-aligned global read (wrap keeps 4-alignment).
    auto ldq = [&](int s, int q) -> float4 {
        const int r  = q / QPR;
        const int c4 = q - r * QPR;
        const int gr = (2 * (i0 + OHS * s) - 10 + r) & mask;
        const int gc = (c0 + 4 * c4) & mask;
        return *(const float4*)(img + (unsigned)(gr * N + gc));
    };
    auto stq = [&](int q, float4 v) {
        const int r  = q / QPR;
        const int c4 = q - r * QPR;
        *(float4*)&s_in[r * SPITCH + 4 * c4] = v;
    };

    const bool loader = tid >= 128;
    const int  lt     = tid - 128;     // loader index 0..127; quads q = lt + 128k

    float4 pf[7];
    // ---- prologue: loaders stage step 0 ----
    if (loader) {
        #pragma unroll
        for (int k = 0; k < 7; ++k) {
            const int q = lt + 128 * k;
            if (q < NQ) pf[k] = ldq(0, q);
        }
        #pragma unroll
        for (int k = 0; k < 7; ++k) {
            const int q = lt + 128 * k;
            if (q < NQ) stq(q, pf[k]);
        }
    }

    for (int s = 0; s < NSTEP; ++s) {
        __syncthreads();              // s_in(step s) visible; loT free

        // issue next step's loads; in flight across phase 1 + phase 2
        if (loader && (s + 1 < NSTEP)) {
            #pragma unroll
            for (int k = 0; k < 7; ++k) {
                const int q = lt + 128 * k;
                if (q < NQ) pf[k] = ldq(s + 1, q);
            }
        }

        // ---- phase 1: row pass (threads 0..167), 8 output cols per task ----
        if (tid < IN_ROWS * 4) {
            const int m = tid & 3;
            const int r = tid >> 2;
            const float* p = &s_in[r * SPITCH + 16 * m];
            float v[28];
            #pragma unroll
            for (int q = 0; q < 7; ++q)
                *(float4*)&v[4 * q] = *(const float4*)&p[4 * q];
            #pragma unroll
            for (int d = 0; d < 8; ++d) {
                float lo = 0.f, hi = 0.f;
                #pragma unroll
                for (int jc = 0; jc < 12; ++jc)
                    lo += c_lo[jc] * v[2 * d + 13 - jc];
                #pragma unroll
                for (int k = 0; k < 4; ++k)
                    hi += c_hi4[k] * v[2 * d + 9 - k];
                s_loT[(8 * m + d) * TRS + r] = lo;
                s_hiT[(8 * m + d) * TRS + r] = hi;
            }
        }
        __syncthreads();              // loT ready; s_in consumed

        if (!loader) {
            // ---- phase 2: column pass, thread = (col tx, row group g), 4 rows ----
            const int tx = tid & 31;
            const int g  = tid >> 5;  // 0..3
            float l[18], hh[18];
            #pragma unroll
            for (int e = 0; e < 18; ++e) {
                l[e]  = s_loT[tx * TRS + 8 * g + e];
                hh[e] = s_hiT[tx * TRS + 8 * g + e];
            }
            #pragma unroll
            for (int u = 0; u < 4; ++u) {
                float vaa = 0.f, vad = 0.f;
                #pragma unroll
                for (int jr = 0; jr < 12; ++jr) {
                    vaa += c_lo[jr] * l[2 * u + 11 - jr];
                    vad += c_lo[jr] * hh[2 * u + 11 - jr];
                }
                float vda = 0.f, vdd = 0.f;
                #pragma unroll
                for (int k = 0; k < 4; ++k) {
                    vda += c_hi4[k] * l[2 * u + 7 - k];
                    vdd += c_hi4[k] * hh[2 * u + 7 - k];
                }
                const int orow = i0 + OHS * s + 4 * g + u;
                const unsigned ob = (unsigned)((bc * h + orow) * h + j0 + tx);
                aa[ob] = vaa;
                da[ob] = vda;
                ad[ob] = vad;
                dd[ob] = vdd;
            }
        } else if (s + 1 < NSTEP) {
            // ---- loaders: write next tile while phase 2 computes ----
            #pragma unroll
            for (int k = 0; k < 7; ++k) {
                const int q = lt + 128 * k;
                if (q < NQ) stq(q, pf[k]);
            }
        }
    }
}

extern "C" void kernel_launch(void* const* d_in, const int* in_sizes, int n_in,
                              void* d_out, int out_size, void* d_ws, size_t ws_size,
                              hipStream_t stream) {
    const float* x = (const float*)d_in[0];
    float* out = (float*)d_out;
    float* ws  = (float*)d_ws;

    // 24 independent N x N images (8 batch x 3 channels).
    const size_t s512 = (size_t)24 * 512 * 512;
    const size_t s256 = (size_t)24 * 256 * 256;
    const size_t s128 = (size_t)24 * 128 * 128;

    // d_out layout (return order): a | h3(da,ad,dd) | h2(...) | h1(...)
    float* a_out = out;
    float* h3 = out + s128;
    float* h2 = out + 4 * s128;
    float* h1 = out + 4 * s128 + 3 * s256;

    float* aa1 = ws;          // 512^2 intermediate
    float* aa2 = ws + s512;   // 256^2 intermediate
    (void)in_sizes; (void)n_in; (void)out_size; (void)ws_size;

    dim3 blk(256, 1, 1);
    // level 1: 1024 -> 512
    dwt2_level<1024><<<dim3(512 / OW, 512 / ROWS_PB, 24), blk, 0, stream>>>(
        x, aa1, h1, h1 + s512, h1 + 2 * s512);
    // level 2: 512 -> 256
    dwt2_level<512><<<dim3(256 / OW, 256 / ROWS_PB, 24), blk, 0, stream>>>(
        aa1, aa2, h2, h2 + s256, h2 + 2 * s256);
    // level 3: 256 -> 128
    dwt2_level<256><<<dim3(128 / OW, 128 / ROWS_PB, 24), blk, 0, stream>>>(
        aa2, a_out, h3, h3 + s128, h3 + 2 * s128);
}